// Round 1
// baseline (44.845 us; speedup 1.0000x reference)
//
#include <hip/hip_runtime.h>

// GAM_8246337208834
// Reference collapses: energy is constant over j -> energy_new == 0 exactly
// -> softmax == 1/128 exactly -> out[b,c,p] = gamma*(1/128)*sum_c' x1[b,c',p] + x1[b,c,p].
// x2 is mathematically unused. Pure streaming op: read x1 once, write out once.

#define B_DIM 16
#define C_CH 128
#define P_TOTAL 16384          // H*W = 128*128
#define WAVES 8                // waves (ty) per block
#define CPW (C_CH / WAVES)     // 16 channels per wave
#define P_PER_BLOCK 256        // 64 lanes * 4 floats (float4)

__global__ __launch_bounds__(512, 4)  // 512 threads = 8 waves; 4 waves/EU min -> 2 blocks/CU, caps VGPR at 128
void gam_fused(const float* __restrict__ x1,
               const float* __restrict__ gamma,
               float* __restrict__ out) {
    const int lane  = threadIdx.x;       // 0..63
    const int wv    = threadIdx.y;       // 0..7
    const int bidx  = blockIdx.x;        // 0..1023
    const int b     = bidx >> 6;         // / (P_TOTAL / P_PER_BLOCK) = /64
    const int ptile = bidx & 63;
    const int pq    = (ptile * P_PER_BLOCK + lane * 4) >> 2;  // float4 index within a channel

    const float4* __restrict__ x1v  = (const float4*)(x1 + (size_t)b * C_CH * P_TOTAL);
    float4*       __restrict__ outv = (float4*)(out + (size_t)b * C_CH * P_TOTAL);

    // Load 16 channels (float4 each) into registers; accumulate partial channel-sum.
    float4 v[CPW];
    float4 s = make_float4(0.f, 0.f, 0.f, 0.f);
    #pragma unroll
    for (int i = 0; i < CPW; ++i) {
        const int c = wv * CPW + i;
        v[i] = x1v[(size_t)c * (P_TOTAL / 4) + pq];
        s.x += v[i].x; s.y += v[i].y; s.z += v[i].z; s.w += v[i].w;
    }

    // Cross-wave reduction of the channel partial sums (8 partials per p-quad).
    __shared__ float4 lds[WAVES][64];
    lds[wv][lane] = s;
    __syncthreads();
    float4 t = lds[0][lane];
    #pragma unroll
    for (int w = 1; w < WAVES; ++w) {
        const float4 u = lds[w][lane];
        t.x += u.x; t.y += u.y; t.z += u.z; t.w += u.w;
    }

    const float g = gamma[0] * (1.0f / 128.0f);
    const float4 m = make_float4(g * t.x, g * t.y, g * t.z, g * t.w);

    // out = gamma * mean + x1 (x1 still in registers -> single HBM read of x1).
    #pragma unroll
    for (int i = 0; i < CPW; ++i) {
        const int c = wv * CPW + i;
        float4 o;
        o.x = m.x + v[i].x; o.y = m.y + v[i].y;
        o.z = m.z + v[i].z; o.w = m.w + v[i].w;
        outv[(size_t)c * (P_TOTAL / 4) + pq] = o;
    }
}

extern "C" void kernel_launch(void* const* d_in, const int* in_sizes, int n_in,
                              void* d_out, int out_size, void* d_ws, size_t ws_size,
                              hipStream_t stream) {
    const float* x1    = (const float*)d_in[0];
    // d_in[1] (x2) is mathematically unused by the reference result.
    const float* gamma = (const float*)d_in[2];
    float* out = (float*)d_out;

    dim3 block(64, WAVES);                          // 512 threads
    dim3 grid(B_DIM * (P_TOTAL / P_PER_BLOCK));     // 16 * 64 = 1024 blocks
    hipLaunchKernelGGL(gam_fused, grid, block, 0, stream, x1, gamma, out);
}